// Round 7
// baseline (131.833 us; speedup 1.0000x reference)
//
#include <hip/hip_runtime.h>

// Q=32, S=25, L=64, F=256, H=64
// out[q,s,i,f] = sum_j softmax_j( sum_h tanh(Wq[q,i,h]*Wh[s,j,h]) ) * hs[s,j,f]
// Wq = (qs @ W^T + b) * 2*log2(e)  (pre-scaled: exp2 arg ready), Wh = hs @ W^T + b
// tanh(x) = 1 - 2/(1+exp2(2log2e*x)); per-row constant 64 drops under softmax.
// 4 h-terms share one v_rcp (clamp 30: den<=2^122 safe).
// r13: r6-r12 ledger: all scheduling knobs null; duration ~= SUM of pipe terms
// (LDS ~20us + VALU + trans) with no overlap, and r8 shows LDS-instr cuts
// alone don't convert. Decisive experiment: REMOVE the LDS/VMEM pipe from the
// score loop entirely. New layout: wave owns a 16-col j-stripe -> B loads are
// wave-uniform -> compiler emits s_load (SMEM pipe); A = lane's own row in 64
// VGPRs (loaded once). Inner loop = pure VALU/trans with SGPR operands.
// 64x64 block (grid 800 = q*s), scores -> LDS once for cross-wave softmax,
// PV re-tiled 4 m-tiles/wave. Per-term math identical to r7/r10.
// total - attn - prep ~= 63-70us is FIXED harness overhead; optimize attn only.

#define NQ 32
#define NS 25
#define NL 64
#define NF 256
#define NH 64

#define K2LOG2E 2.8853900817779268f

typedef __attribute__((ext_vector_type(8))) short bf16x8;
typedef __attribute__((ext_vector_type(4))) float f32x4;
typedef __attribute__((ext_vector_type(2))) float v2f;

__device__ inline unsigned short f2bf(float x) {  // RNE
    union { float f; unsigned int u; } v; v.f = x;
    unsigned int r = v.u + 0x7fffu + ((v.u >> 16) & 1u);
    return (unsigned short)(r >> 16);
}

__device__ inline void cvt_hilo(float4 a, float4 b, bf16x8* hi, bf16x8* lo) {
    float x[8] = {a.x, a.y, a.z, a.w, b.x, b.y, b.z, b.w};
    bf16x8 h8, l8;
#pragma unroll
    for (int i = 0; i < 8; ++i) {
        union { float f; unsigned int u; } v; v.f = x[i];
        unsigned short hh = (unsigned short)(v.u >> 16);
        h8[i] = (short)hh;
        union { unsigned int u; float f; } hf; hf.u = (unsigned int)hh << 16;
        union { float f; unsigned int u; } rv; rv.f = x[i] - hf.f;
        l8[i] = (short)(unsigned short)(rv.u >> 16);
    }
    *hi = h8; *lo = l8;
}

// ---------------- prep kernel (unchanged: ~3-7us, not the bottleneck) ----
#define PROJ_BLOCKS 114
__global__ __launch_bounds__(256) void prep_kernel(
    const float* __restrict__ qs, const float* __restrict__ hs,
    const float* __restrict__ W, const float* __restrict__ b,
    float* __restrict__ Wqs, float* __restrict__ Whs,
    unsigned short* __restrict__ hsT)
{
    __shared__ unsigned short T[64 * 72];
    const int t = threadIdx.x;
    const int bid = blockIdx.x;

    if (bid < PROJ_BLOCKS) {
        const int w = t >> 6, lane = t & 63;
        const int m15 = lane & 15, quad = lane >> 4;
        const int r0 = bid * 32 + (w & 1) * 16;
        const int h0 = (w >> 1) * 32;
        const bool is_q = (r0 < 2048);
        const float* Xrow = is_q ? (qs + (size_t)(r0 + m15) * NF)
                                 : (hs + (size_t)(r0 - 2048 + m15) * NF);
        f32x4 acc[2] = {(f32x4){0.f,0.f,0.f,0.f}, (f32x4){0.f,0.f,0.f,0.f}};

#pragma unroll 2
        for (int kk = 0; kk < 8; ++kk) {
            const int f0 = kk * 32 + quad * 8;
            bf16x8 xhi, xlo;
            cvt_hilo(*(const float4*)(Xrow + f0), *(const float4*)(Xrow + f0 + 4),
                     &xhi, &xlo);
#pragma unroll
            for (int nt = 0; nt < 2; ++nt) {
                const float* Wrow = W + (size_t)(h0 + nt * 16 + m15) * NF + f0;
                bf16x8 whi, wlo;
                cvt_hilo(*(const float4*)(Wrow), *(const float4*)(Wrow + 4),
                         &whi, &wlo);
                acc[nt] = __builtin_amdgcn_mfma_f32_16x16x32_bf16(xhi, whi, acc[nt], 0, 0, 0);
                acc[nt] = __builtin_amdgcn_mfma_f32_16x16x32_bf16(xhi, wlo, acc[nt], 0, 0, 0);
                acc[nt] = __builtin_amdgcn_mfma_f32_16x16x32_bf16(xlo, whi, acc[nt], 0, 0, 0);
            }
        }
#pragma unroll
        for (int nt = 0; nt < 2; ++nt) {
            const int h = h0 + nt * 16 + m15;
            const float bias = b[h];
#pragma unroll
            for (int r = 0; r < 4; ++r) {
                const int row = r0 + quad * 4 + r;
                const float v = acc[nt][r] + bias;
                if (is_q) Wqs[(size_t)row * NH + h] = v * K2LOG2E;
                else      Whs[(size_t)(row - 2048) * NH + h] = v;
            }
        }
    } else {
        const int b2 = bid - PROJ_BLOCKS;
        const int s = b2 >> 2;
        const int f0 = (b2 & 3) * 64;
        const float4* h4p = (const float4*)(hs + (size_t)s * NL * NF);
#pragma unroll
        for (int u = 0; u < 4; ++u) {
            int idx = t + 256 * u;
            int j = idx >> 4, fq = idx & 15;
            float4 v = h4p[j * 64 + (f0 >> 2) + fq];
            T[(4 * fq + 0) * 72 + j] = f2bf(v.x);
            T[(4 * fq + 1) * 72 + j] = f2bf(v.y);
            T[(4 * fq + 2) * 72 + j] = f2bf(v.z);
            T[(4 * fq + 3) * 72 + j] = f2bf(v.w);
        }
        __syncthreads();
#pragma unroll
        for (int u = 0; u < 2; ++u) {
            int idx = t + 256 * u;
            int fl = idx >> 3, jg = idx & 7;
            uint4 v = *(const uint4*)&T[fl * 72 + jg * 8];
            *(uint4*)&hsT[(size_t)(s * 256 + f0 + fl) * 64 + jg * 8] = v;
        }
    }
}

// 8 terms (4 h-values x 2 columns): combine fully packed over the column pair.
// sum accumulates {col0, col1} contributions of sum_h 1/(1+exp2(x)).
// Identical math/order to the verified r7 kernel.
__device__ inline void score8(v2f alo, v2f ahi, float4 b0, float4 b1, v2f* sum) {
    const v2f vcl = {30.f, 30.f};
    v2f xlo0 = __builtin_elementwise_min(alo * (v2f){b0.x, b0.y}, vcl);
    v2f xhi0 = __builtin_elementwise_min(ahi * (v2f){b0.z, b0.w}, vcl);
    v2f xlo1 = __builtin_elementwise_min(alo * (v2f){b1.x, b1.y}, vcl);
    v2f xhi1 = __builtin_elementwise_min(ahi * (v2f){b1.z, b1.w}, vcl);
    v2f E0 = { __builtin_amdgcn_exp2f(xlo0[0]), __builtin_amdgcn_exp2f(xlo1[0]) };
    v2f E1 = { __builtin_amdgcn_exp2f(xlo0[1]), __builtin_amdgcn_exp2f(xlo1[1]) };
    v2f E2 = { __builtin_amdgcn_exp2f(xhi0[0]), __builtin_amdgcn_exp2f(xhi1[0]) };
    v2f E3 = { __builtin_amdgcn_exp2f(xhi0[1]), __builtin_amdgcn_exp2f(xhi1[1]) };
    v2f S01 = E0 + E1, S23 = E2 + E3;
    v2f D01 = __builtin_elementwise_fma(E0, E1, S01) + (v2f){1.f, 1.f};
    v2f D23 = __builtin_elementwise_fma(E2, E3, S23) + (v2f){1.f, 1.f};
    v2f U01 = S01 + (v2f){2.f, 2.f};
    v2f U23 = S23 + (v2f){2.f, 2.f};
    v2f NUM = __builtin_elementwise_fma(U01, D23, U23 * D01);
    v2f PROD = D01 * D23;
    v2f R = { __builtin_amdgcn_rcpf(PROD[0]), __builtin_amdgcn_rcpf(PROD[1]) };
    *sum = __builtin_elementwise_fma(NUM, R, *sum);
}

// ---------------- fused attention kernel ----------------
// Grid 800: (q, s). Block: 64 i x 64 j, 4 waves. Wave wv owns cols
// [16wv,16wv+16); lane = i. B loads wave-uniform -> s_load (SMEM pipe);
// A row in 64 VGPRs. Score loop has ZERO LDS/VMEM instructions.
// LDS: score f32 [64][68] @0 (17408B) | att bf16 [64][72] @17408 (9216B)
//      = 26624 B. VGPR ~100 -> 4 waves/SIMD -> 4 blocks/CU.
#define SC_S 68
#define ATT_F 4352          // float offset of att region

__global__ __launch_bounds__(256, 4) void attn_kernel(
    const float* __restrict__ Wqs, const float* __restrict__ Whs,
    const unsigned short* __restrict__ hsT, float* __restrict__ out)
{
    __shared__ float smem[6656];
    const int t = threadIdx.x;
    const int bid = blockIdx.x;
    const int s = bid % NS;
    const int q = bid / NS;
    const int lane = t & 63;
    const int wv = t >> 6;
    const int wvu = __builtin_amdgcn_readfirstlane(wv);

    // ---- A row (i = lane) -> 32 v2f (64 VGPR), loaded once (L2-resident) ----
    v2f a2[32];
    {
        const float4* arow = (const float4*)(Wqs + ((size_t)q * NL + lane) * NH);
#pragma unroll
        for (int k = 0; k < 16; ++k) {
            float4 v = arow[k];
            a2[2 * k]     = (v2f){v.x, v.y};
            a2[2 * k + 1] = (v2f){v.z, v.w};
        }
    }

    // ---- scores: pure VALU/trans loop; B via wave-uniform (scalar) loads ----
    {
        const float* Bb = Whs + ((size_t)s * NL + wvu * 16) * NH;
#pragma unroll 2
        for (int jp = 0; jp < 8; ++jp) {
            const float* bj0 = Bb + jp * NH;        // col 16wv + jp
            const float* bj1 = Bb + (jp + 8) * NH;  // col 16wv + jp + 8
            v2f sum = {0.f, 0.f};
#pragma unroll
            for (int h4 = 0; h4 < 16; ++h4) {
                float4 b0 = *(const float4*)(bj0 + 4 * h4);  // uniform -> s_load
                float4 b1 = *(const float4*)(bj1 + 4 * h4);
                score8(a2[2 * h4], a2[2 * h4 + 1], b0, b1, &sum);
            }
            smem[lane * SC_S + wvu * 16 + jp]     = sum[0];
            smem[lane * SC_S + wvu * 16 + jp + 8] = sum[1];
        }
    }
    __syncthreads();

    // ---- softmax over j per row; thread (si = t>>2, g = t&3) -> 16 cols ----
    {
        const int si = t >> 2;
        const int g = t & 3;
        const float* srow = &smem[si * SC_S + g * 16];
        float4 s0 = *(const float4*)(srow);
        float4 s1 = *(const float4*)(srow + 4);
        float4 s2 = *(const float4*)(srow + 8);
        float4 s3 = *(const float4*)(srow + 12);
        float sc[16] = {s0.x, s0.y, s0.z, s0.w, s1.x, s1.y, s1.z, s1.w,
                        s2.x, s2.y, s2.z, s2.w, s3.x, s3.y, s3.z, s3.w};
        float mn = sc[0];
#pragma unroll
        for (int k = 1; k < 16; ++k) mn = fminf(mn, sc[k]);
        mn = fminf(mn, __shfl_xor(mn, 1));   // lanes 4k..4k+3 share si
        mn = fminf(mn, __shfl_xor(mn, 2));
        float p[16];
        float d = 0.f;
#pragma unroll
        for (int k = 0; k < 16; ++k) {
            p[k] = __builtin_amdgcn_exp2f((mn - sc[k]) * K2LOG2E);
            d += p[k];
        }
        d += __shfl_xor(d, 1);
        d += __shfl_xor(d, 2);
        const float inv = __builtin_amdgcn_rcpf(d);
        unsigned int w[8];
#pragma unroll
        for (int k = 0; k < 8; ++k)
            w[k] = (unsigned int)f2bf(p[2 * k] * inv)
                 | ((unsigned int)f2bf(p[2 * k + 1] * inv) << 16);
        unsigned short* att = (unsigned short*)(smem + ATT_F);  // [64][72]
        *(uint4*)&att[si * 72 + g * 16]     = (uint4){w[0], w[1], w[2], w[3]};
        *(uint4*)&att[si * 72 + g * 16 + 8] = (uint4){w[4], w[5], w[6], w[7]};
    }
    __syncthreads();

    // ---- PV via bf16 MFMA: [64 x 64j] @ [64j x 256f]; wave wv -> f in [64wv,64wv+64) ----
    const int m15 = lane & 15;
    const int quad = lane >> 4;
    const unsigned short* attc = (const unsigned short*)(smem + ATT_F);

    bf16x8 afr[4][2];  // [m-tile][k]: att[m*16 + m15][k*32 + quad*8 ..]
#pragma unroll
    for (int m = 0; m < 4; ++m)
#pragma unroll
        for (int k = 0; k < 2; ++k)
            afr[m][k] = *(const bf16x8*)((const char*)attc
                            + (m * 16 + m15) * 144 + k * 64 + quad * 16);

    const unsigned short* hsTs = hsT + (size_t)s * NF * NL;
    const size_t obase = (size_t)(q * NS + s) * NL * NF;

#pragma unroll
    for (int nh = 0; nh < 2; ++nh) {   // two f-halves: acc pressure halved
        f32x4 acc[4][2];
#pragma unroll
        for (int m = 0; m < 4; ++m)
#pragma unroll
            for (int n = 0; n < 2; ++n) acc[m][n] = (f32x4){0.f, 0.f, 0.f, 0.f};

#pragma unroll
        for (int k = 0; k < 2; ++k) {
            bf16x8 bfr[2];
#pragma unroll
            for (int n = 0; n < 2; ++n)
                bfr[n] = *(const bf16x8*)(hsTs
                            + (size_t)((wv * 4 + nh * 2 + n) * 16 + m15) * 64
                            + k * 32 + quad * 8);
#pragma unroll
            for (int n = 0; n < 2; ++n)
#pragma unroll
                for (int m = 0; m < 4; ++m)
                    acc[m][n] = __builtin_amdgcn_mfma_f32_16x16x32_bf16(
                        afr[m][k], bfr[n], acc[m][n], 0, 0, 0);
        }
        // C layout: col(f)=lane&15, row(i)=m*16+quad*4+reg
#pragma unroll
        for (int m = 0; m < 4; ++m)
#pragma unroll
            for (int n = 0; n < 2; ++n)
#pragma unroll
                for (int r = 0; r < 4; ++r)
                    out[obase + (size_t)(m * 16 + quad * 4 + r) * NF
                        + (wv * 4 + nh * 2 + n) * 16 + m15] = acc[m][n][r];
    }
}

extern "C" void kernel_launch(void* const* d_in, const int* in_sizes, int n_in,
                              void* d_out, int out_size, void* d_ws, size_t ws_size,
                              hipStream_t stream) {
    const float* qs = (const float*)d_in[0];
    const float* hs = (const float*)d_in[1];
    const float* W  = (const float*)d_in[2];
    const float* b  = (const float*)d_in[3];
    float* out = (float*)d_out;

    float* Wqs = (float*)d_ws;                         // 131072 f
    float* Whs = Wqs + NQ * NL * NH;                   // 102400 f
    unsigned short* hsT = (unsigned short*)(Whs + NS * NL * NH);  // 409600 bf16

    prep_kernel<<<PROJ_BLOCKS + NS * 4, 256, 0, stream>>>(qs, hs, W, b, Wqs, Whs, hsT);
    attn_kernel<<<NQ * NS, 256, 0, stream>>>(Wqs, Whs, hsT, out);
}